// Round 1
// baseline (87550.916 us; speedup 1.0000x reference)
//
#include <hip/hip_runtime.h>
#include <math.h>

// Problem constants (fixed by setup_inputs)
#define BB 512     // batch
#define HH 1024    // hidden
#define OO 512     // output
#define KC 1536    // O + H (concat input width)
#define G4H 4096   // 4*H
#define TT 256     // out_len

// ---------------------------------------------------------------------------
// Prep: tiled transpose  dst[(drow0 + c)*dstride + r] = src[r*C + c]
// ---------------------------------------------------------------------------
__global__ __launch_bounds__(256) void transpose_kernel(
    const float* __restrict__ src, float* __restrict__ dst,
    int R, int C, int dstride, int drow0)
{
    __shared__ float tile[32][33];
    int c0 = blockIdx.x * 32, r0 = blockIdx.y * 32;
    int x = threadIdx.x;         // 0..31
    for (int y = threadIdx.y; y < 32; y += 8)
        tile[y][x] = src[(size_t)(r0 + y) * C + c0 + x];
    __syncthreads();
    for (int y = threadIdx.y; y < 32; y += 8)
        dst[(size_t)(drow0 + c0 + y) * dstride + r0 + x] = tile[x][y];
}

// bias = b_ih + b_hh ; xh0 = [zeros | h0] ; c = c0
__global__ __launch_bounds__(256) void prep_misc(
    const float* __restrict__ b_ih, const float* __restrict__ b_hh,
    const float* __restrict__ h0, const float* __restrict__ c0,
    float* __restrict__ bias, float* __restrict__ xh0, float* __restrict__ cst)
{
    int idx0 = blockIdx.x * blockDim.x + threadIdx.x;
    int stride = gridDim.x * blockDim.x;
    for (int i = idx0; i < G4H; i += stride) bias[i] = b_ih[i] + b_hh[i];
    for (int i = idx0; i < BB * KC; i += stride) {
        int b = i / KC, p = i - b * KC;
        xh0[i] = (p < OO) ? 0.f : h0[b * HH + (p - OO)];
    }
    for (int i = idx0; i < BB * HH; i += stride) cst[i] = c0[i];
}

// ---------------------------------------------------------------------------
// gates GEMM + fused LSTM cell update.
// Block: 32 batch rows x 64 j-cols, computing all 4 gates for that j-range.
// grid = (16 j-tiles, 16 b-tiles), 256 threads.
// ---------------------------------------------------------------------------
__global__ __launch_bounds__(256) void gates_kernel(
    const float* __restrict__ xh_in,   // [B][KC]
    float* __restrict__ xh_out,        // [B][KC]  (h written at +OO)
    float* __restrict__ cst,           // [B][H]   in-place
    const float* __restrict__ WcatT,   // [KC][4H]
    const float* __restrict__ bias)    // [4H]
{
    const int j0 = blockIdx.x * 64;
    const int b0 = blockIdx.y * 32;
    const int tid = threadIdx.x;
    const int tx = tid & 15;   // col group: cols tx*4..tx*4+3
    const int ty = tid >> 4;   // row group: rows ty*2, ty*2+1

    __shared__ float As[16][33];      // [k][b] padded
    __shared__ float Bs[4][16][64];   // [gate][k][j]

    float acc[4][2][4] = {};

    for (int k0 = 0; k0 < KC; k0 += 16) {
        // stage A: 32 rows x 16 k
        #pragma unroll
        for (int e = tid; e < 512; e += 256) {
            int k = e & 15, b = e >> 4;
            As[k][b] = xh_in[(size_t)(b0 + b) * KC + k0 + k];
        }
        // stage B: 4 gates x 16 k x 64 j, float4
        #pragma unroll
        for (int e = tid; e < 1024; e += 256) {
            int j4 = e & 15, k = (e >> 4) & 15, g = e >> 8;
            *(float4*)&Bs[g][k][j4 * 4] =
                *(const float4*)&WcatT[(size_t)(k0 + k) * G4H + g * HH + j0 + j4 * 4];
        }
        __syncthreads();
        #pragma unroll
        for (int kk = 0; kk < 16; ++kk) {
            float a0 = As[kk][ty * 2 + 0];
            float a1 = As[kk][ty * 2 + 1];
            #pragma unroll
            for (int g = 0; g < 4; ++g) {
                float4 bv = *(const float4*)&Bs[g][kk][tx * 4];
                acc[g][0][0] += a0 * bv.x; acc[g][0][1] += a0 * bv.y;
                acc[g][0][2] += a0 * bv.z; acc[g][0][3] += a0 * bv.w;
                acc[g][1][0] += a1 * bv.x; acc[g][1][1] += a1 * bv.y;
                acc[g][1][2] += a1 * bv.z; acc[g][1][3] += a1 * bv.w;
            }
        }
        __syncthreads();
    }

    // fused LSTM cell update
    #pragma unroll
    for (int r = 0; r < 2; ++r) {
        int b = b0 + ty * 2 + r;
        #pragma unroll
        for (int i2 = 0; i2 < 4; ++i2) {
            int j = j0 + tx * 4 + i2;
            float gi = acc[0][r][i2] + bias[0 * HH + j];
            float gf = acc[1][r][i2] + bias[1 * HH + j];
            float gg = acc[2][r][i2] + bias[2 * HH + j];
            float go = acc[3][r][i2] + bias[3 * HH + j];
            float iv = 1.f / (1.f + expf(-gi));
            float fv = 1.f / (1.f + expf(-gf));
            float gv = tanhf(gg);
            float ov = 1.f / (1.f + expf(-go));
            float cold = cst[(size_t)b * HH + j];
            float cnew = fv * cold + iv * gv;
            float hnew = ov * tanhf(cnew);
            cst[(size_t)b * HH + j] = cnew;
            xh_out[(size_t)b * KC + OO + j] = hnew;
        }
    }
}

// ---------------------------------------------------------------------------
// logits GEMM: [B][H] (h in xh at +OO) x WoT[H][O] -> logits[B][O]
// grid = (8 o-tiles, 16 b-tiles), 256 threads; 32x64 tiles.
// ---------------------------------------------------------------------------
__global__ __launch_bounds__(256) void logits_kernel(
    const float* __restrict__ xh,    // [B][KC], h at +OO
    const float* __restrict__ WoT,   // [H][O]
    float* __restrict__ logits)      // [B][O]
{
    const int o0 = blockIdx.x * 64;
    const int b0 = blockIdx.y * 32;
    const int tid = threadIdx.x;
    const int tx = tid & 15;
    const int ty = tid >> 4;

    __shared__ float As[16][33];
    __shared__ float Bs[16][64];

    float acc[2][4] = {};

    for (int k0 = 0; k0 < HH; k0 += 16) {
        #pragma unroll
        for (int e = tid; e < 512; e += 256) {
            int k = e & 15, b = e >> 4;
            As[k][b] = xh[(size_t)(b0 + b) * KC + OO + k0 + k];
        }
        { // 16 k x 64 o = 1024 floats = 256 float4
            int e = tid;
            int j4 = e & 15, k = e >> 4;
            *(float4*)&Bs[k][j4 * 4] =
                *(const float4*)&WoT[(size_t)(k0 + k) * OO + o0 + j4 * 4];
        }
        __syncthreads();
        #pragma unroll
        for (int kk = 0; kk < 16; ++kk) {
            float a0 = As[kk][ty * 2 + 0];
            float a1 = As[kk][ty * 2 + 1];
            float4 bv = *(const float4*)&Bs[kk][tx * 4];
            acc[0][0] += a0 * bv.x; acc[0][1] += a0 * bv.y;
            acc[0][2] += a0 * bv.z; acc[0][3] += a0 * bv.w;
            acc[1][0] += a1 * bv.x; acc[1][1] += a1 * bv.y;
            acc[1][2] += a1 * bv.z; acc[1][3] += a1 * bv.w;
        }
        __syncthreads();
    }
    #pragma unroll
    for (int r = 0; r < 2; ++r)
        #pragma unroll
        for (int i2 = 0; i2 < 4; ++i2)
            logits[(size_t)(b0 + ty * 2 + r) * OO + o0 + tx * 4 + i2] = acc[r][i2];
}

// ---------------------------------------------------------------------------
// softmax over O=512 per batch row; writes out slice and next-step x.
// ---------------------------------------------------------------------------
__global__ __launch_bounds__(512) void softmax_kernel(
    const float* __restrict__ logits, const float* __restrict__ b_out,
    float* __restrict__ out_slice, float* __restrict__ xh_next)
{
    const int b = blockIdx.x;
    const int o = threadIdx.x;
    float v = logits[(size_t)b * OO + o] + b_out[o];

    __shared__ float red[8];
    // block max
    float m = v;
    #pragma unroll
    for (int off = 32; off > 0; off >>= 1) m = fmaxf(m, __shfl_down(m, off, 64));
    if ((o & 63) == 0) red[o >> 6] = m;
    __syncthreads();
    if (o == 0) {
        float mm = red[0];
        #pragma unroll
        for (int w = 1; w < 8; ++w) mm = fmaxf(mm, red[w]);
        red[0] = mm;
    }
    __syncthreads();
    m = red[0];
    float e = expf(v - m);
    __syncthreads();   // red reuse
    // block sum
    float s = e;
    #pragma unroll
    for (int off = 32; off > 0; off >>= 1) s += __shfl_down(s, off, 64);
    if ((o & 63) == 0) red[o >> 6] = s;
    __syncthreads();
    if (o == 0) {
        float ss = 0.f;
        #pragma unroll
        for (int w = 0; w < 8; ++w) ss += red[w];
        red[0] = ss;
    }
    __syncthreads();
    float y = e / red[0];
    out_slice[(size_t)b * OO + o] = y;
    xh_next[(size_t)b * KC + o] = y;
}

// ---------------------------------------------------------------------------
extern "C" void kernel_launch(void* const* d_in, const int* in_sizes, int n_in,
                              void* d_out, int out_size, void* d_ws, size_t ws_size,
                              hipStream_t stream)
{
    const float* h0    = (const float*)d_in[0];
    const float* c0    = (const float*)d_in[1];
    const float* W_ih  = (const float*)d_in[2];   // [4H][O]
    const float* W_hh  = (const float*)d_in[3];   // [4H][H]
    const float* b_ih  = (const float*)d_in[4];
    const float* b_hh  = (const float*)d_in[5];
    const float* W_out = (const float*)d_in[6];   // [O][H]
    const float* b_out = (const float*)d_in[7];
    float* out = (float*)d_out;

    float* ws     = (float*)d_ws;
    float* WcatT  = ws;                       // [KC][4H]   = 6291456
    float* WoT    = WcatT + (size_t)KC * G4H; // [H][O]     = 524288
    float* bias   = WoT + (size_t)HH * OO;    // 4096
    float* xh0    = bias + G4H;               // [B][KC]    = 786432
    float* xh1    = xh0 + (size_t)BB * KC;    // [B][KC]
    float* cst    = xh1 + (size_t)BB * KC;    // [B][H]     = 524288
    float* logits = cst + (size_t)BB * HH;    // [B][O]     = 262144

    dim3 tb(32, 8);
    // WcatT rows 0..511 <- W_ih cols; rows 512..1535 <- W_hh cols
    transpose_kernel<<<dim3(512 / 32, 4096 / 32), tb, 0, stream>>>(W_ih, WcatT, G4H, OO, G4H, 0);
    transpose_kernel<<<dim3(1024 / 32, 4096 / 32), tb, 0, stream>>>(W_hh, WcatT, G4H, HH, G4H, OO);
    transpose_kernel<<<dim3(1024 / 32, 512 / 32), tb, 0, stream>>>(W_out, WoT, OO, HH, OO, 0);
    prep_misc<<<512, 256, 0, stream>>>(b_ih, b_hh, h0, c0, bias, xh0, cst);

    for (int t = 0; t < TT; ++t) {
        float* xin  = (t & 1) ? xh1 : xh0;
        float* xout = (t & 1) ? xh0 : xh1;
        gates_kernel<<<dim3(16, 16), 256, 0, stream>>>(xin, xout, cst, WcatT, bias);
        logits_kernel<<<dim3(8, 16), 256, 0, stream>>>(xout, WoT, logits);
        softmax_kernel<<<512, 512, 0, stream>>>(
            logits, b_out, out + (size_t)(TT - 1 - t) * BB * OO, xout);
    }
}

// Round 2
// 12617.342 us; speedup vs baseline: 6.9389x; 6.9389x over previous
//
#include <hip/hip_runtime.h>
#include <math.h>

#define BB 512     // batch
#define HH 1024    // hidden
#define OO 512     // output
#define KC 1536    // O + H
#define G4H 4096   // 4*H
#define TT 256     // out_len

typedef _Float16 half8 __attribute__((ext_vector_type(8)));
typedef float float16v __attribute__((ext_vector_type(16)));

// ---------------------------------------------------------------------------
// Prep: Wcat f16, gate-interleaved permutation.
// p = jt*128 + g*32 + jr  <->  original row n = g*1024 + jt*32 + jr
// Wcat[p][k] = k<512 ? W_ih[n][k] : W_hh[n][k-512]
// ---------------------------------------------------------------------------
__global__ __launch_bounds__(256) void conv_wcat(
    const float* __restrict__ W_ih, const float* __restrict__ W_hh,
    _Float16* __restrict__ Wcat)
{
    int k = blockIdx.x * 256 + threadIdx.x;  // 0..1535
    int p = blockIdx.y;                      // 0..4095
    int g = (p >> 5) & 3, jt = p >> 7, jr = p & 31;
    int n = g * HH + jt * 32 + jr;
    float v = (k < OO) ? W_ih[(size_t)n * OO + k] : W_hh[(size_t)n * HH + (k - OO)];
    Wcat[(size_t)p * KC + k] = (_Float16)v;
}

__global__ __launch_bounds__(256) void conv_wout(
    const float* __restrict__ W_out, _Float16* __restrict__ Wout16)
{
    int k = blockIdx.x * 256 + threadIdx.x;  // 0..1023
    int o = blockIdx.y;                      // 0..511
    Wout16[(size_t)o * HH + k] = (_Float16)W_out[(size_t)o * HH + k];
}

// bias_p (permuted, fp32), xh0 = [0 | f16(h0)], cst = c0 (fp32)
__global__ __launch_bounds__(256) void prep_misc(
    const float* __restrict__ b_ih, const float* __restrict__ b_hh,
    const float* __restrict__ h0, const float* __restrict__ c0,
    float* __restrict__ bias_p, _Float16* __restrict__ xh0, float* __restrict__ cst)
{
    int idx0 = blockIdx.x * blockDim.x + threadIdx.x;
    int stride = gridDim.x * blockDim.x;
    for (int p = idx0; p < G4H; p += stride) {
        int g = (p >> 5) & 3, jt = p >> 7, jr = p & 31;
        int n = g * HH + jt * 32 + jr;
        bias_p[p] = b_ih[n] + b_hh[n];
    }
    for (int i = idx0; i < BB * KC; i += stride) {
        int b = i / KC, q = i - b * KC;
        xh0[i] = (q < OO) ? (_Float16)0.f : (_Float16)h0[b * HH + (q - OO)];
    }
    for (int i = idx0; i < BB * HH; i += stride) cst[i] = c0[i];
}

// ---------------------------------------------------------------------------
// gates GEMM (f16 MFMA 32x32x16) + fused LSTM cell update.
// Block-tile 64 b x 128 p; 4 waves as 2(b) x 2(p); wave-tile 32x64.
// grid = (32 p-tiles, 8 b-tiles) = 256 blocks.
// ---------------------------------------------------------------------------
__global__ __launch_bounds__(256) void gates_mfma(
    const _Float16* __restrict__ xh_in,   // [B][KC]
    _Float16* __restrict__ xh_out,        // [B][KC]  (h at +OO)
    float* __restrict__ cst,              // [B][H]
    const _Float16* __restrict__ Wcat,    // [4096][KC] permuted
    const float* __restrict__ bias_p)     // [4096] permuted
{
    const int pt = blockIdx.x;            // p0 = pt*128
    const int bt = blockIdx.y;            // b0 = bt*64
    const int p0 = pt * 128, b0 = bt * 64;
    const int tid = threadIdx.x;
    const int l = tid & 63, w = tid >> 6;
    const int wm = w & 1, wn = w >> 1;
    const int lr = l & 31, lh = l >> 5;

    __shared__ __align__(16) char smem[33792];
    _Float16* Af = (_Float16*)smem;                 // [64][72]
    _Float16* Bf = (_Float16*)(smem + 64 * 72 * 2); // [128][72]

    float16v acc[2];
    #pragma unroll
    for (int r = 0; r < 16; ++r) { acc[0][r] = 0.f; acc[1][r] = 0.f; }

    for (int k0 = 0; k0 < KC; k0 += 64) {
        #pragma unroll
        for (int pg = 0; pg < 2; ++pg) {   // A: 64 rows x 8 chunks
            int s = tid + pg * 256;
            int r = s >> 3, c = s & 7;
            *(float4*)&Af[r * 72 + c * 8] =
                *(const float4*)&xh_in[(size_t)(b0 + r) * KC + k0 + c * 8];
        }
        #pragma unroll
        for (int pg = 0; pg < 4; ++pg) {   // B: 128 rows x 8 chunks
            int s = tid + pg * 256;
            int r = s >> 3, c = s & 7;
            *(float4*)&Bf[r * 72 + c * 8] =
                *(const float4*)&Wcat[(size_t)(p0 + r) * KC + k0 + c * 8];
        }
        __syncthreads();
        #pragma unroll
        for (int ks = 0; ks < 4; ++ks) {
            half8 a  = *(const half8*)&Af[(wm * 32 + lr) * 72 + ks * 16 + lh * 8];
            half8 bq0 = *(const half8*)&Bf[(wn * 64 + lr) * 72 + ks * 16 + lh * 8];
            half8 bq1 = *(const half8*)&Bf[(wn * 64 + 32 + lr) * 72 + ks * 16 + lh * 8];
            acc[0] = __builtin_amdgcn_mfma_f32_32x32x16_f16(a, bq0, acc[0], 0, 0, 0);
            acc[1] = __builtin_amdgcn_mfma_f32_32x32x16_f16(a, bq1, acc[1], 0, 0, 0);
        }
        __syncthreads();
    }

    // exchange gate preactivations through LDS (reuse smem)
    float* exch = (float*)smem;   // [64][132]
    #pragma unroll
    for (int sn = 0; sn < 2; ++sn)
        #pragma unroll
        for (int r = 0; r < 16; ++r) {
            int rloc = (r & 3) + 8 * (r >> 2) + 4 * lh;
            exch[(wm * 32 + rloc) * 132 + wn * 64 + sn * 32 + lr] = acc[sn][r];
        }
    __syncthreads();

    // cell update: thread covers b-local = tid>>2, jr = (tid&3)*8 + u
    int bl = tid >> 2;
    int b = b0 + bl;
    #pragma unroll
    for (int u = 0; u < 8; ++u) {
        int jr = (tid & 3) * 8 + u;
        float gi = exch[bl * 132 +       jr] + bias_p[p0 +       jr];
        float gf = exch[bl * 132 + 32 + jr] + bias_p[p0 + 32 + jr];
        float gg = exch[bl * 132 + 64 + jr] + bias_p[p0 + 64 + jr];
        float go = exch[bl * 132 + 96 + jr] + bias_p[p0 + 96 + jr];
        float iv = 1.f / (1.f + expf(-gi));
        float fv = 1.f / (1.f + expf(-gf));
        float gv = tanhf(gg);
        float ov = 1.f / (1.f + expf(-go));
        int j = pt * 32 + jr;
        float cold = cst[(size_t)b * HH + j];
        float cnew = fv * cold + iv * gv;
        float hnew = ov * tanhf(cnew);
        cst[(size_t)b * HH + j] = cnew;
        xh_out[(size_t)b * KC + OO + j] = (_Float16)hnew;
    }
}

// ---------------------------------------------------------------------------
// logits GEMM: h[512x1024] x W_out^T -> logits[512x512]  (f16 MFMA 32x32x16)
// Block-tile 64 b x 64 o; 4 waves 2x2; wave-tile 32x32. grid (8,8).
// ---------------------------------------------------------------------------
__global__ __launch_bounds__(256) void logits_mfma(
    const _Float16* __restrict__ xh,     // h at +OO
    const _Float16* __restrict__ Wout16, // [512][1024]
    float* __restrict__ logits)          // [B][O]
{
    const int o0 = blockIdx.x * 64, b0 = blockIdx.y * 64;
    const int tid = threadIdx.x;
    const int l = tid & 63, w = tid >> 6;
    const int wm = w & 1, wn = w >> 1;
    const int lr = l & 31, lh = l >> 5;

    __shared__ __align__(16) _Float16 Ah[64 * 72];
    __shared__ __align__(16) _Float16 Bo[64 * 72];

    float16v acc;
    #pragma unroll
    for (int r = 0; r < 16; ++r) acc[r] = 0.f;

    for (int k0 = 0; k0 < HH; k0 += 64) {
        #pragma unroll
        for (int pg = 0; pg < 2; ++pg) {
            int s = tid + pg * 256;
            int r = s >> 3, c = s & 7;
            *(float4*)&Ah[r * 72 + c * 8] =
                *(const float4*)&xh[(size_t)(b0 + r) * KC + OO + k0 + c * 8];
            *(float4*)&Bo[r * 72 + c * 8] =
                *(const float4*)&Wout16[(size_t)(o0 + r) * HH + k0 + c * 8];
        }
        __syncthreads();
        #pragma unroll
        for (int ks = 0; ks < 4; ++ks) {
            half8 a = *(const half8*)&Ah[(wm * 32 + lr) * 72 + ks * 16 + lh * 8];
            half8 bq = *(const half8*)&Bo[(wn * 32 + lr) * 72 + ks * 16 + lh * 8];
            acc = __builtin_amdgcn_mfma_f32_32x32x16_f16(a, bq, acc, 0, 0, 0);
        }
        __syncthreads();
    }
    #pragma unroll
    for (int r = 0; r < 16; ++r) {
        int rloc = (r & 3) + 8 * (r >> 2) + 4 * lh;
        logits[(size_t)(b0 + wm * 32 + rloc) * OO + o0 + wn * 32 + lr] = acc[r];
    }
}

// ---------------------------------------------------------------------------
// softmax over O=512 per row; writes out slice (fp32) and next x (f16).
// ---------------------------------------------------------------------------
__global__ __launch_bounds__(512) void softmax_kernel(
    const float* __restrict__ logits, const float* __restrict__ b_out,
    float* __restrict__ out_slice, _Float16* __restrict__ xh_next)
{
    const int b = blockIdx.x;
    const int o = threadIdx.x;
    float v = logits[(size_t)b * OO + o] + b_out[o];

    __shared__ float red[8];
    float m = v;
    #pragma unroll
    for (int off = 32; off > 0; off >>= 1) m = fmaxf(m, __shfl_down(m, off, 64));
    if ((o & 63) == 0) red[o >> 6] = m;
    __syncthreads();
    if (o == 0) {
        float mm = red[0];
        #pragma unroll
        for (int ww = 1; ww < 8; ++ww) mm = fmaxf(mm, red[ww]);
        red[0] = mm;
    }
    __syncthreads();
    m = red[0];
    float e = expf(v - m);
    __syncthreads();
    float s = e;
    #pragma unroll
    for (int off = 32; off > 0; off >>= 1) s += __shfl_down(s, off, 64);
    if ((o & 63) == 0) red[o >> 6] = s;
    __syncthreads();
    if (o == 0) {
        float ss = 0.f;
        #pragma unroll
        for (int ww = 0; ww < 8; ++ww) ss += red[ww];
        red[0] = ss;
    }
    __syncthreads();
    float y = e / red[0];
    out_slice[(size_t)b * OO + o] = y;
    xh_next[(size_t)b * KC + o] = (_Float16)y;
}

// ---------------------------------------------------------------------------
extern "C" void kernel_launch(void* const* d_in, const int* in_sizes, int n_in,
                              void* d_out, int out_size, void* d_ws, size_t ws_size,
                              hipStream_t stream)
{
    const float* h0    = (const float*)d_in[0];
    const float* c0    = (const float*)d_in[1];
    const float* W_ih  = (const float*)d_in[2];   // [4H][O]
    const float* W_hh  = (const float*)d_in[3];   // [4H][H]
    const float* b_ih  = (const float*)d_in[4];
    const float* b_hh  = (const float*)d_in[5];
    const float* W_out = (const float*)d_in[6];   // [O][H]
    const float* b_out = (const float*)d_in[7];
    float* out = (float*)d_out;

    char* wsb = (char*)d_ws;
    _Float16* Wcat   = (_Float16*)wsb;                 wsb += (size_t)G4H * KC * 2;
    _Float16* Wout16 = (_Float16*)wsb;                 wsb += (size_t)OO * HH * 2;
    float*    bias_p = (float*)wsb;                    wsb += (size_t)G4H * 4;
    _Float16* xh0    = (_Float16*)wsb;                 wsb += (size_t)BB * KC * 2;
    _Float16* xh1    = (_Float16*)wsb;                 wsb += (size_t)BB * KC * 2;
    float*    cst    = (float*)wsb;                    wsb += (size_t)BB * HH * 4;
    float*    logits = (float*)wsb;                    wsb += (size_t)BB * OO * 4;

    conv_wcat<<<dim3(KC / 256, G4H), 256, 0, stream>>>(W_ih, W_hh, Wcat);
    conv_wout<<<dim3(HH / 256, OO), 256, 0, stream>>>(W_out, Wout16);
    prep_misc<<<512, 256, 0, stream>>>(b_ih, b_hh, h0, c0, bias_p, xh0, cst);

    for (int t = 0; t < TT; ++t) {
        _Float16* xin  = (t & 1) ? xh1 : xh0;
        _Float16* xout = (t & 1) ? xh0 : xh1;
        gates_mfma<<<dim3(32, 8), 256, 0, stream>>>(xin, xout, cst, Wcat, bias_p);
        logits_mfma<<<dim3(8, 8), 256, 0, stream>>>(xout, Wout16, logits);
        softmax_kernel<<<512, 512, 0, stream>>>(
            logits, b_out, out + (size_t)(TT - 1 - t) * BB * OO, xout);
    }
}

// Round 3
// 8078.471 us; speedup vs baseline: 10.8376x; 1.5618x over previous
//
#include <hip/hip_runtime.h>
#include <math.h>

#define BB 512     // batch
#define HH 1024    // hidden
#define OO 512     // output
#define KC 1536    // O + H
#define G4H 4096   // 4*H
#define TT 256     // out_len

typedef _Float16 half8 __attribute__((ext_vector_type(8)));
typedef float f32x4 __attribute__((ext_vector_type(4)));

// async global->LDS DMA, 16B per lane; LDS dest = wave-uniform base + lane*16
__device__ __forceinline__ void dma16(const void* g, void* l) {
    __builtin_amdgcn_global_load_lds(
        (const __attribute__((address_space(1))) void*)g,
        (__attribute__((address_space(3))) void*)l, 16, 0, 0);
}

// ---------------------------------------------------------------------------
// Prep (unchanged from round 2): Wcat f16 gate-interleaved, Wout f16, bias, state
// p = jt*128 + g*32 + jr  <->  original row n = g*1024 + jt*32 + jr
// ---------------------------------------------------------------------------
__global__ __launch_bounds__(256) void conv_wcat(
    const float* __restrict__ W_ih, const float* __restrict__ W_hh,
    _Float16* __restrict__ Wcat)
{
    int k = blockIdx.x * 256 + threadIdx.x;
    int p = blockIdx.y;
    int g = (p >> 5) & 3, jt = p >> 7, jr = p & 31;
    int n = g * HH + jt * 32 + jr;
    float v = (k < OO) ? W_ih[(size_t)n * OO + k] : W_hh[(size_t)n * HH + (k - OO)];
    Wcat[(size_t)p * KC + k] = (_Float16)v;
}

__global__ __launch_bounds__(256) void conv_wout(
    const float* __restrict__ W_out, _Float16* __restrict__ Wout16)
{
    int k = blockIdx.x * 256 + threadIdx.x;
    int o = blockIdx.y;
    Wout16[(size_t)o * HH + k] = (_Float16)W_out[(size_t)o * HH + k];
}

__global__ __launch_bounds__(256) void prep_misc(
    const float* __restrict__ b_ih, const float* __restrict__ b_hh,
    const float* __restrict__ h0, const float* __restrict__ c0,
    float* __restrict__ bias_p, _Float16* __restrict__ xh0, float* __restrict__ cst)
{
    int idx0 = blockIdx.x * blockDim.x + threadIdx.x;
    int stride = gridDim.x * blockDim.x;
    for (int p = idx0; p < G4H; p += stride) {
        int g = (p >> 5) & 3, jt = p >> 7, jr = p & 31;
        int n = g * HH + jt * 32 + jr;
        bias_p[p] = b_ih[n] + b_hh[n];
    }
    for (int i = idx0; i < BB * KC; i += stride) {
        int b = i / KC, q = i - b * KC;
        xh0[i] = (q < OO) ? (_Float16)0.f : (_Float16)h0[b * HH + (q - OO)];
    }
    for (int i = idx0; i < BB * HH; i += stride) cst[i] = c0[i];
}

// ---------------------------------------------------------------------------
// gates: 64b x 128p block-tile, BK=128, global_load_lds staging, XOR-swizzled
// LDS, 16x16x32 MFMA, wave-tile 32x64 (2x4 frags). grid (32 pt, 8 bt) = 256.
// LDS layout: tile[row][chunk'] (chunk=8 f16=16B) where chunk' = chunk ^ (row&7).
// ---------------------------------------------------------------------------
__global__ __launch_bounds__(256) void gates_mfma(
    const _Float16* __restrict__ xh_in,   // [B][KC]
    _Float16* __restrict__ xh_out,        // [B][KC] (h at +OO)
    float* __restrict__ cst,              // [B][H]
    const _Float16* __restrict__ Wcat,    // [4096][KC] permuted
    const float* __restrict__ bias_p)     // [4096] permuted
{
    const int pt = blockIdx.x;
    const int p0 = pt * 128, b0 = blockIdx.y * 64;
    const int tid = threadIdx.x;
    const int l = tid & 63, w = tid >> 6;
    const int wm = w & 1, wn = w >> 1;      // 2(b) x 2(p) waves
    const int l15 = l & 15, l4 = l >> 4;    // frag row / k-group
    const int lo3 = l & 7;

    __shared__ __align__(16) char smem[49152];
    _Float16* Af = (_Float16*)smem;              // [64][128]
    _Float16* Bf = (_Float16*)(smem + 16384);    // [128][128]

    f32x4 acc[2][4];
    #pragma unroll
    for (int fm = 0; fm < 2; ++fm)
        #pragma unroll
        for (int fn = 0; fn < 4; ++fn)
            acc[fm][fn] = (f32x4){0.f, 0.f, 0.f, 0.f};

    for (int k0 = 0; k0 < KC; k0 += 128) {
        // A: 64 rows x 16 chunks; 16 DMA calls (4/wave, 4 rows each)
        #pragma unroll
        for (int j = 0; j < 4; ++j) {
            int r0 = (w * 4 + j) * 4;
            int row = r0 + l4;                     // l4 in 0..3
            int c = (l15) ^ (row & 7);             // data chunk for slot l15
            dma16(&xh_in[(size_t)(b0 + row) * KC + k0 + c * 8],
                  &Af[(size_t)(w * 4 + j) * 512]);
        }
        // B: 128 rows x 16 chunks; 32 DMA calls (8/wave)
        #pragma unroll
        for (int j = 0; j < 8; ++j) {
            int r0 = (w * 8 + j) * 4;
            int row = r0 + l4;
            int c = (l15) ^ (row & 7);
            dma16(&Wcat[(size_t)(p0 + row) * KC + k0 + c * 8],
                  &Bf[(size_t)(w * 8 + j) * 512]);
        }
        __syncthreads();   // compiler drains vmcnt before s_barrier

        #pragma unroll
        for (int ks = 0; ks < 4; ++ks) {
            int cc = (ks * 4 + l4) ^ lo3;          // swizzled chunk slot
            half8 af[2], bf[4];
            #pragma unroll
            for (int fm = 0; fm < 2; ++fm) {
                int R = wm * 32 + fm * 16 + l15;
                af[fm] = *(const half8*)&Af[R * 128 + cc * 8];
            }
            #pragma unroll
            for (int fn = 0; fn < 4; ++fn) {
                int S = wn * 64 + fn * 16 + l15;
                bf[fn] = *(const half8*)&Bf[S * 128 + cc * 8];
            }
            #pragma unroll
            for (int fm = 0; fm < 2; ++fm)
                #pragma unroll
                for (int fn = 0; fn < 4; ++fn)
                    acc[fm][fn] = __builtin_amdgcn_mfma_f32_16x16x32_f16(
                        af[fm], bf[fn], acc[fm][fn], 0, 0, 0);
        }
        __syncthreads();
    }

    // exchange preactivations through LDS (reuse smem), stride 133 fp32
    float* exch = (float*)smem;   // [64][133]
    #pragma unroll
    for (int fm = 0; fm < 2; ++fm)
        #pragma unroll
        for (int fn = 0; fn < 4; ++fn)
            #pragma unroll
            for (int r = 0; r < 4; ++r) {
                int row = wm * 32 + fm * 16 + l4 * 4 + r;   // batch-local
                int col = wn * 64 + fn * 16 + l15;          // p-local
                exch[row * 133 + col] = acc[fm][fn][r];
            }
    __syncthreads();

    // cell update: thread -> batch-local bl = tid>>2, jr = (tid&3)*8 + u
    int bl = tid >> 2;
    int b = b0 + bl;
    int jbase = (tid & 3) * 8;
    float cv[8], hv[8];
    float cold[8];
    *(float4*)&cold[0] = *(const float4*)&cst[(size_t)b * HH + pt * 32 + jbase];
    *(float4*)&cold[4] = *(const float4*)&cst[(size_t)b * HH + pt * 32 + jbase + 4];
    #pragma unroll
    for (int u = 0; u < 8; ++u) {
        int jr = jbase + u;
        float gi = exch[bl * 133 +       jr] + bias_p[p0 +       jr];
        float gf = exch[bl * 133 + 32 + jr] + bias_p[p0 + 32 + jr];
        float gg = exch[bl * 133 + 64 + jr] + bias_p[p0 + 64 + jr];
        float go = exch[bl * 133 + 96 + jr] + bias_p[p0 + 96 + jr];
        float iv = 1.f / (1.f + expf(-gi));
        float fv = 1.f / (1.f + expf(-gf));
        float gv = tanhf(gg);
        float ov = 1.f / (1.f + expf(-go));
        float cnew = fv * cold[u] + iv * gv;
        cv[u] = cnew;
        hv[u] = ov * tanhf(cnew);
    }
    *(float4*)&cst[(size_t)b * HH + pt * 32 + jbase]     = *(const float4*)&cv[0];
    *(float4*)&cst[(size_t)b * HH + pt * 32 + jbase + 4] = *(const float4*)&cv[4];
    half8 hh;
    #pragma unroll
    for (int u = 0; u < 8; ++u) hh[u] = (_Float16)hv[u];
    *(half8*)&xh_out[(size_t)b * KC + OO + pt * 32 + jbase] = hh;
}

// ---------------------------------------------------------------------------
// logits: 32b x 32o tiles, grid (16,16)=256 blocks, 128 threads (2 waves),
// BK=128, DMA staging + swizzle, bias fused in epilogue.
// ---------------------------------------------------------------------------
__global__ __launch_bounds__(128) void logits_mfma(
    const _Float16* __restrict__ xh,      // h at +OO
    const _Float16* __restrict__ Wout16,  // [O][H]
    const float* __restrict__ b_out,
    float* __restrict__ logits)           // [B][O]
{
    const int o0 = blockIdx.x * 32, b0 = blockIdx.y * 32;
    const int tid = threadIdx.x;
    const int l = tid & 63, w = tid >> 6;  // 2 waves: batch halves
    const int l15 = l & 15, l4 = l >> 4, lo3 = l & 7;

    __shared__ __align__(16) _Float16 Ah[32 * 128];
    __shared__ __align__(16) _Float16 Bo[32 * 128];

    f32x4 acc[2];
    acc[0] = (f32x4){0.f, 0.f, 0.f, 0.f};
    acc[1] = (f32x4){0.f, 0.f, 0.f, 0.f};

    for (int k0 = 0; k0 < HH; k0 += 128) {
        #pragma unroll
        for (int j = 0; j < 4; ++j) {       // A: 32 rows, 8 calls total
            int row = (w * 4 + j) * 4 + l4;
            int c = l15 ^ (row & 7);
            dma16(&xh[(size_t)(b0 + row) * KC + OO + k0 + c * 8],
                  &Ah[(size_t)(w * 4 + j) * 512]);
        }
        #pragma unroll
        for (int j = 0; j < 4; ++j) {       // B: 32 rows (o), 8 calls total
            int row = (w * 4 + j) * 4 + l4;
            int c = l15 ^ (row & 7);
            dma16(&Wout16[(size_t)(o0 + row) * HH + k0 + c * 8],
                  &Bo[(size_t)(w * 4 + j) * 512]);
        }
        __syncthreads();
        #pragma unroll
        for (int ks = 0; ks < 4; ++ks) {
            int cc = (ks * 4 + l4) ^ lo3;
            int R = w * 16 + l15;
            half8 a = *(const half8*)&Ah[R * 128 + cc * 8];
            #pragma unroll
            for (int fn = 0; fn < 2; ++fn) {
                int S = fn * 16 + l15;
                half8 bq = *(const half8*)&Bo[S * 128 + cc * 8];
                acc[fn] = __builtin_amdgcn_mfma_f32_16x16x32_f16(a, bq, acc[fn], 0, 0, 0);
            }
        }
        __syncthreads();
    }
    #pragma unroll
    for (int fn = 0; fn < 2; ++fn)
        #pragma unroll
        for (int r = 0; r < 4; ++r) {
            int row = b0 + w * 16 + l4 * 4 + r;
            int col = o0 + fn * 16 + l15;
            logits[(size_t)row * OO + col] = acc[fn][r] + b_out[col];
        }
}

// ---------------------------------------------------------------------------
// softmax: one wave per row, shuffle-only. grid 128 x 256 threads.
// logits already include b_out.
// ---------------------------------------------------------------------------
__global__ __launch_bounds__(256) void softmax_kernel(
    const float* __restrict__ logits,
    float* __restrict__ out_slice, _Float16* __restrict__ xh_next)
{
    const int w = threadIdx.x >> 6, l = threadIdx.x & 63;
    const int b = blockIdx.x * 4 + w;
    float v[8];
    *(float4*)&v[0] = *(const float4*)&logits[(size_t)b * OO + l * 8];
    *(float4*)&v[4] = *(const float4*)&logits[(size_t)b * OO + l * 8 + 4];

    float m = v[0];
    #pragma unroll
    for (int u = 1; u < 8; ++u) m = fmaxf(m, v[u]);
    #pragma unroll
    for (int off = 1; off < 64; off <<= 1) m = fmaxf(m, __shfl_xor(m, off, 64));

    float s = 0.f;
    #pragma unroll
    for (int u = 0; u < 8; ++u) { v[u] = expf(v[u] - m); s += v[u]; }
    #pragma unroll
    for (int off = 1; off < 64; off <<= 1) s += __shfl_xor(s, off, 64);

    float inv = 1.f / s;
    float y[8];
    half8 hh;
    #pragma unroll
    for (int u = 0; u < 8; ++u) { y[u] = v[u] * inv; hh[u] = (_Float16)y[u]; }
    *(float4*)&out_slice[(size_t)b * OO + l * 8]     = *(const float4*)&y[0];
    *(float4*)&out_slice[(size_t)b * OO + l * 8 + 4] = *(const float4*)&y[4];
    *(half8*)&xh_next[(size_t)b * KC + l * 8] = hh;
}

// ---------------------------------------------------------------------------
extern "C" void kernel_launch(void* const* d_in, const int* in_sizes, int n_in,
                              void* d_out, int out_size, void* d_ws, size_t ws_size,
                              hipStream_t stream)
{
    const float* h0    = (const float*)d_in[0];
    const float* c0    = (const float*)d_in[1];
    const float* W_ih  = (const float*)d_in[2];
    const float* W_hh  = (const float*)d_in[3];
    const float* b_ih  = (const float*)d_in[4];
    const float* b_hh  = (const float*)d_in[5];
    const float* W_out = (const float*)d_in[6];
    const float* b_out = (const float*)d_in[7];
    float* out = (float*)d_out;

    char* wsb = (char*)d_ws;
    _Float16* Wcat   = (_Float16*)wsb;                 wsb += (size_t)G4H * KC * 2;
    _Float16* Wout16 = (_Float16*)wsb;                 wsb += (size_t)OO * HH * 2;
    float*    bias_p = (float*)wsb;                    wsb += (size_t)G4H * 4;
    _Float16* xh0    = (_Float16*)wsb;                 wsb += (size_t)BB * KC * 2;
    _Float16* xh1    = (_Float16*)wsb;                 wsb += (size_t)BB * KC * 2;
    float*    cst    = (float*)wsb;                    wsb += (size_t)BB * HH * 4;
    float*    logits = (float*)wsb;                    wsb += (size_t)BB * OO * 4;

    conv_wcat<<<dim3(KC / 256, G4H), 256, 0, stream>>>(W_ih, W_hh, Wcat);
    conv_wout<<<dim3(HH / 256, OO), 256, 0, stream>>>(W_out, Wout16);
    prep_misc<<<512, 256, 0, stream>>>(b_ih, b_hh, h0, c0, bias_p, xh0, cst);

    for (int t = 0; t < TT; ++t) {
        _Float16* xin  = (t & 1) ? xh1 : xh0;
        _Float16* xout = (t & 1) ? xh0 : xh1;
        gates_mfma<<<dim3(32, 8), 256, 0, stream>>>(xin, xout, cst, Wcat, bias_p);
        logits_mfma<<<dim3(16, 16), 128, 0, stream>>>(xout, Wout16, b_out, logits);
        softmax_kernel<<<128, 256, 0, stream>>>(
            logits, out + (size_t)(TT - 1 - t) * BB * OO, xout);
    }
}